// Round 1
// baseline (1234.858 us; speedup 1.0000x reference)
//
#include <hip/hip_runtime.h>
#include <stdint.h>

// Problem constants
#define TT 1024     // tokens
#define HH 2048     // hidden
#define NE 32       // routed experts
#define II 1024     // intermediate
#define NTOPK 6
#define SCALEF 2.5f

typedef __attribute__((ext_vector_type(4))) float f32x4;
typedef __attribute__((ext_vector_type(8))) __bf16 bf16x8;

#define GLD16(g, l)                                                                         \
  __builtin_amdgcn_global_load_lds((const __attribute__((address_space(1))) void*)(g),      \
                                   (__attribute__((address_space(3))) void*)(l), 16, 0, 0)

__device__ __forceinline__ unsigned bf16rne(float f) {
    unsigned u = __builtin_bit_cast(unsigned, f);
    return (u + 0x7FFFu + ((u >> 16) & 1u)) >> 16;
}
__device__ __forceinline__ unsigned pack2(float lo, float hi) {
    return bf16rne(lo) | (bf16rne(hi) << 16);
}

// ---------------------------------------------------------------------------
// Kernel 1: convert hidden_states fp32 -> bf16 (row-major [T][H]);
// also initialize "expert 32" (= shared expert) token list with identity.
__global__ void init_convert(const float* __restrict__ x, unsigned short* __restrict__ xb,
                             int* __restrict__ cnt, int* __restrict__ tlist,
                             float* __restrict__ twgt) {
    int gid = blockIdx.x * 256 + threadIdx.x;   // 524288 threads, 4 floats each
    const float4* x4 = (const float4*)x;
    float4 v = x4[gid];
    uint2 o;
    o.x = pack2(v.x, v.y);
    o.y = pack2(v.z, v.w);
    ((uint2*)xb)[gid] = o;
    if (gid < TT) {
        tlist[(NE << 10) + gid] = gid;
        twgt[(NE << 10) + gid] = 1.0f;   // shared expert: weight 1.0, no SCALE
    }
    if (gid == 0) cnt[NE] = TT;
}

// ---------------------------------------------------------------------------
// Kernel 2: router. One wave per token. fp32 logits, sigmoid scoring,
// grouped top-k (noaux_tc) done serially on lane 0 (32 experts = trivial).
__global__ void router_kernel(const float* __restrict__ x, const float* __restrict__ gw,
                              const float* __restrict__ bias, int* __restrict__ cnt,
                              int* __restrict__ tlist, float* __restrict__ twgt) {
    int t = blockIdx.x;
    int lane = threadIdx.x;
    int e = lane & 31, h = lane >> 5;
    const float* xr = x + (size_t)t * HH;
    float acc = 0.f;
    #pragma unroll 4
    for (int k = h; k < HH; k += 2)
        acc += xr[k] * gw[k * NE + e];
    acc += __shfl_down(acc, 32);

    __shared__ float sc[NE], sb[NE];
    if (lane < NE) {
        float s = 1.f / (1.f + expf(-acc));
        sc[e] = s;
        sb[e] = s + bias[e];
    }
    __syncthreads();
    if (lane == 0) {
        // group scores: sum of top-2 biased scores within each group of 4
        float gs[8];
        for (int g = 0; g < 8; g++) {
            float m1 = -1e30f, m2 = -1e30f;
            for (int j = 0; j < 4; j++) {
                float v = sb[g * 4 + j];
                if (v > m1) { m2 = m1; m1 = v; }
                else if (v > m2) { m2 = v; }
            }
            gs[g] = m1 + m2;
        }
        unsigned gmask = 0;
        for (int r = 0; r < 4; r++) {          // top-4 groups (ties -> lowest idx)
            float best = -1e30f; int bi = 0;
            for (int g = 0; g < 8; g++)
                if (!((gmask >> g) & 1) && gs[g] > best) { best = gs[g]; bi = g; }
            gmask |= 1u << bi;
        }
        int ids[NTOPK]; float wsv[NTOPK]; float sum = 0.f;
        unsigned sel = 0;
        for (int r = 0; r < NTOPK; r++) {      // top-6 experts among allowed groups
            float best = -1e30f; int bi = 0;
            for (int ee = 0; ee < NE; ee++) {
                if (!((gmask >> (ee >> 2)) & 1)) continue;
                if ((sel >> ee) & 1) continue;
                if (sb[ee] > best) { best = sb[ee]; bi = ee; }
            }
            sel |= 1u << bi;
            ids[r] = bi; wsv[r] = sc[bi]; sum += sc[bi];
        }
        float inv = SCALEF / sum;              // fold routed_scaling_factor here
        for (int r = 0; r < NTOPK; r++) {
            int ee = ids[r];
            int slot = atomicAdd(&cnt[ee], 1);
            tlist[(ee << 10) + slot] = t;
            twgt[(ee << 10) + slot] = wsv[r] * inv;
        }
    }
}

// ---------------------------------------------------------------------------
// Kernel 3: gate_up GEMM + silu*mul + weight, bf16 MFMA 16x16x32.
// Block: 128 rows (token-expert pairs) x 64 act cols (needs 64 gate + 64 up W cols).
// W is fp32 [K][N]; converted to bf16 and transposed into LDS [n][k] on the fly.
__global__ __launch_bounds__(256, 2)
void gu_gemm(const unsigned short* __restrict__ xb,
             const float* __restrict__ wgu, const float* __restrict__ shgu,
             const int* __restrict__ tlist, const float* __restrict__ twgt,
             const int* __restrict__ cnt, unsigned short* __restrict__ act) {
    int e = blockIdx.z;
    int count = cnt[e];
    int m0 = blockIdx.y * 128;
    if (m0 >= count) return;
    int n0 = blockIdx.x * 64;
    const float* wb = (e < NE) ? (wgu + (size_t)e * HH * (2 * II)) : shgu;
    const int* tl = tlist + (e << 10);

    __shared__ __align__(16) unsigned short xs[128 * 32];   // A tile [m][k] bf16
    __shared__ __align__(16) unsigned short wg[64 * 40];    // gate W [n][kpad=40]
    __shared__ __align__(16) unsigned short wu[64 * 40];    // up   W [n][kpad=40]

    int tid = threadIdx.x;
    int lane = tid & 63, wv = tid >> 6;
    int q = lane >> 4, c = lane & 15;

    // --- A staging: 2 rounds of 64 rows; wave wv covers rows wv*16..wv*16+15
    int arow = wv * 16 + (lane >> 2);
    int akc = (lane & 3) * 8;
    int tok0 = (m0 + arow < count) ? tl[m0 + arow] : 0;
    int tok1 = (m0 + arow + 64 < count) ? tl[m0 + arow + 64] : 0;
    const unsigned short* ag0 = xb + (size_t)tok0 * HH + akc;
    const unsigned short* ag1 = xb + (size_t)tok1 * HH + akc;
    unsigned short* al0 = xs + (wv * 16) * 32;       // wave-uniform LDS base
    unsigned short* al1 = xs + (64 + wv * 16) * 32;

    // --- B staging mapping: kp-major in lane for 2-way-free LDS banks
    int kp = tid & 15, ig = tid >> 4;                // kp: k-pair 0..15, ig: n-group 0..15
    int n4 = ig * 4;
    const float* wpbase = wb + (size_t)(kp * 2) * (2 * II) + n0 + n4;
    unsigned* wgd = (unsigned*)wg;
    unsigned* wud = (unsigned*)wu;
    int di = n4 * 20 + kp;                           // dword idx, row = 20 dwords

    f32x4 accg[2][4] = {};
    f32x4 accu[2][4] = {};

    for (int k0 = 0; k0 < HH; k0 += 32) {
        GLD16(ag0 + k0, al0);
        GLD16(ag1 + k0, al1);
        const float* wp = wpbase + (size_t)k0 * (2 * II);
        float4 g0 = *(const float4*)(wp);
        float4 g1 = *(const float4*)(wp + 2 * II);           // next k row
        float4 u0 = *(const float4*)(wp + II);               // up cols at +1024
        float4 u1 = *(const float4*)(wp + 2 * II + II);
        wgd[di]      = pack2(g0.x, g1.x);
        wgd[di + 20] = pack2(g0.y, g1.y);
        wgd[di + 40] = pack2(g0.z, g1.z);
        wgd[di + 60] = pack2(g0.w, g1.w);
        wud[di]      = pack2(u0.x, u1.x);
        wud[di + 20] = pack2(u0.y, u1.y);
        wud[di + 40] = pack2(u0.z, u1.z);
        wud[di + 60] = pack2(u0.w, u1.w);
        __syncthreads();
        bf16x8 a0 = *(const bf16x8*)(xs + (wv * 32 + c) * 32 + q * 8);
        bf16x8 a1 = *(const bf16x8*)(xs + (wv * 32 + 16 + c) * 32 + q * 8);
        #pragma unroll
        for (int tn = 0; tn < 4; tn++) {
            bf16x8 bg = *(const bf16x8*)(wg + (tn * 16 + c) * 40 + q * 8);
            bf16x8 bu = *(const bf16x8*)(wu + (tn * 16 + c) * 40 + q * 8);
            accg[0][tn] = __builtin_amdgcn_mfma_f32_16x16x32_bf16(a0, bg, accg[0][tn], 0, 0, 0);
            accg[1][tn] = __builtin_amdgcn_mfma_f32_16x16x32_bf16(a1, bg, accg[1][tn], 0, 0, 0);
            accu[0][tn] = __builtin_amdgcn_mfma_f32_16x16x32_bf16(a0, bu, accu[0][tn], 0, 0, 0);
            accu[1][tn] = __builtin_amdgcn_mfma_f32_16x16x32_bf16(a1, bu, accu[1][tn], 0, 0, 0);
        }
        __syncthreads();
    }

    // epilogue: act = silu(g)*u * weight, bf16 store
    const float* twp = twgt + (e << 10);
    #pragma unroll
    for (int tm = 0; tm < 2; tm++) {
        int mlb = wv * 32 + tm * 16 + q * 4;
        #pragma unroll
        for (int r = 0; r < 4; r++) {
            int m = m0 + mlb + r;
            if (m < count) {
                float w = twp[m];
                size_t rowbase = ((size_t)(e << 10) + m) * II + n0;
                #pragma unroll
                for (int tn = 0; tn < 4; tn++) {
                    float g = accg[tm][tn][r];
                    float u = accu[tm][tn][r];
                    float a = (g / (1.f + __expf(-g))) * u * w;
                    act[rowbase + tn * 16 + c] = (unsigned short)bf16rne(a);
                }
            }
        }
    }
}

// ---------------------------------------------------------------------------
// Kernel 4: down GEMM + scatter-add into out. Block: 128 pairs x 128 H-cols.
__global__ __launch_bounds__(256, 2)
void down_gemm(const unsigned short* __restrict__ act,
               const float* __restrict__ wd, const float* __restrict__ shd,
               const int* __restrict__ tlist, const int* __restrict__ cnt,
               float* __restrict__ out) {
    int e = blockIdx.z;
    int count = cnt[e];
    int m0 = blockIdx.y * 128;
    if (m0 >= count) return;
    int n0 = blockIdx.x * 128;
    const float* wb = (e < NE) ? (wd + (size_t)e * II * HH) : shd;
    const int* tl = tlist + (e << 10);

    __shared__ __align__(16) unsigned short as_[128 * 32];
    __shared__ __align__(16) unsigned short bs[128 * 40];

    int tid = threadIdx.x;
    int lane = tid & 63, wv = tid >> 6;
    int q = lane >> 4, c = lane & 15;

    const unsigned short* ag =
        act + ((size_t)(e << 10) + m0 + wv * 16 + (lane >> 2)) * II + (lane & 3) * 8;
    unsigned short* al0 = as_ + (wv * 16) * 32;
    unsigned short* al1 = as_ + (64 + wv * 16) * 32;

    int kp = tid & 15, ig = tid >> 4;
    int n4 = ig * 4;
    const float* wpbase = wb + (size_t)(kp * 2) * HH + n0 + n4;
    unsigned* bd = (unsigned*)bs;
    int di0 = n4 * 20 + kp;
    int di1 = (n4 + 64) * 20 + kp;

    f32x4 acc[2][8] = {};

    for (int k0 = 0; k0 < II; k0 += 32) {
        GLD16(ag + k0, al0);
        GLD16(ag + (size_t)64 * II + k0, al1);
        const float* wp = wpbase + (size_t)k0 * HH;
        float4 x0 = *(const float4*)(wp);
        float4 x1 = *(const float4*)(wp + HH);
        float4 y0 = *(const float4*)(wp + 64);
        float4 y1 = *(const float4*)(wp + HH + 64);
        bd[di0]      = pack2(x0.x, x1.x);
        bd[di0 + 20] = pack2(x0.y, x1.y);
        bd[di0 + 40] = pack2(x0.z, x1.z);
        bd[di0 + 60] = pack2(x0.w, x1.w);
        bd[di1]      = pack2(y0.x, y1.x);
        bd[di1 + 20] = pack2(y0.y, y1.y);
        bd[di1 + 40] = pack2(y0.z, y1.z);
        bd[di1 + 60] = pack2(y0.w, y1.w);
        __syncthreads();
        bf16x8 a0 = *(const bf16x8*)(as_ + (wv * 32 + c) * 32 + q * 8);
        bf16x8 a1 = *(const bf16x8*)(as_ + (wv * 32 + 16 + c) * 32 + q * 8);
        #pragma unroll
        for (int tn = 0; tn < 8; tn++) {
            bf16x8 b = *(const bf16x8*)(bs + (tn * 16 + c) * 40 + q * 8);
            acc[0][tn] = __builtin_amdgcn_mfma_f32_16x16x32_bf16(a0, b, acc[0][tn], 0, 0, 0);
            acc[1][tn] = __builtin_amdgcn_mfma_f32_16x16x32_bf16(a1, b, acc[1][tn], 0, 0, 0);
        }
        __syncthreads();
    }

    #pragma unroll
    for (int tm = 0; tm < 2; tm++) {
        int mlb = wv * 32 + tm * 16 + q * 4;
        #pragma unroll
        for (int r = 0; r < 4; r++) {
            int m = m0 + mlb + r;
            if (m < count) {
                int tok = tl[m];
                float* op = out + (size_t)tok * HH + n0 + c;
                #pragma unroll
                for (int tn = 0; tn < 8; tn++)
                    unsafeAtomicAdd(op + tn * 16, acc[tm][tn][r]);
            }
        }
    }
}

// ---------------------------------------------------------------------------
extern "C" void kernel_launch(void* const* d_in, const int* in_sizes, int n_in,
                              void* d_out, int out_size, void* d_ws, size_t ws_size,
                              hipStream_t stream) {
    const float* x    = (const float*)d_in[0];
    const float* gw   = (const float*)d_in[1];
    const float* bias = (const float*)d_in[2];
    const float* wgu  = (const float*)d_in[3];
    const float* wd   = (const float*)d_in[4];
    const float* shgu = (const float*)d_in[5];
    const float* shd  = (const float*)d_in[6];
    float* out = (float*)d_out;

    // workspace layout (~74 MB total)
    char* ws = (char*)d_ws;
    int*   cnt   = (int*)ws;                                   // 256 B (33 used)
    int*   tlist = (int*)(ws + 256);                           // 33*1024*4
    float* twgt  = (float*)(ws + 256 + 33 * 1024 * 4);         // 33*1024*4
    unsigned short* xb  = (unsigned short*)(ws + 256 + 2 * 33 * 1024 * 4);
    unsigned short* act = (unsigned short*)((char*)xb + (size_t)TT * HH * 2);

    hipMemsetAsync(cnt, 0, 256, stream);
    hipMemsetAsync(out, 0, (size_t)out_size * sizeof(float), stream);
    init_convert<<<dim3((TT * HH / 4) / 256), 256, 0, stream>>>(x, xb, cnt, tlist, twgt);
    router_kernel<<<dim3(TT), 64, 0, stream>>>(x, gw, bias, cnt, tlist, twgt);
    gu_gemm<<<dim3(II / 64, 8, NE + 1), 256, 0, stream>>>(xb, wgu, shgu, tlist, twgt, cnt, act);
    down_gemm<<<dim3(HH / 128, 8, NE + 1), 256, 0, stream>>>(act, wd, shd, tlist, cnt, out);
}

// Round 2
// 1228.321 us; speedup vs baseline: 1.0053x; 1.0053x over previous
//
#include <hip/hip_runtime.h>
#include <stdint.h>

// Problem constants
#define TT 1024     // tokens
#define HH 2048     // hidden
#define NE 32       // routed experts
#define II 1024     // intermediate
#define NTOPK 6
#define SCALEF 2.5f

typedef __attribute__((ext_vector_type(4))) float f32x4;
typedef __attribute__((ext_vector_type(8))) __bf16 bf16x8;
typedef unsigned short us;

#define GLD16(g, l)                                                                         \
  __builtin_amdgcn_global_load_lds((const __attribute__((address_space(1))) void*)(g),      \
                                   (__attribute__((address_space(3))) void*)(l), 16, 0, 0)

__device__ __forceinline__ unsigned bf16rne(float f) {
    unsigned u = __builtin_bit_cast(unsigned, f);
    return (u + 0x7FFFu + ((u >> 16) & 1u)) >> 16;
}
__device__ __forceinline__ unsigned pack2(float lo, float hi) {
    return bf16rne(lo) | (bf16rne(hi) << 16);
}

// ---------------------------------------------------------------------------
// Kernel 1: convert hidden_states fp32 -> bf16 (row-major [T][H]);
// also initialize "expert 32" (= shared expert) token list with identity.
__global__ void init_convert(const float* __restrict__ x, us* __restrict__ xb,
                             int* __restrict__ cnt, int* __restrict__ tlist,
                             float* __restrict__ twgt) {
    int gid = blockIdx.x * 256 + threadIdx.x;   // 524288 threads, 4 floats each
    const float4* x4 = (const float4*)x;
    float4 v = x4[gid];
    uint2 o;
    o.x = pack2(v.x, v.y);
    o.y = pack2(v.z, v.w);
    ((uint2*)xb)[gid] = o;
    if (gid < TT) {
        tlist[(NE << 10) + gid] = gid;
        twgt[(NE << 10) + gid] = 1.0f;   // shared expert: weight 1.0, no SCALE
    }
    if (gid == 0) cnt[NE] = TT;
}

// ---------------------------------------------------------------------------
// Kernel 2: router. One wave per token.
__global__ void router_kernel(const float* __restrict__ x, const float* __restrict__ gw,
                              const float* __restrict__ bias, int* __restrict__ cnt,
                              int* __restrict__ tlist, float* __restrict__ twgt) {
    int t = blockIdx.x;
    int lane = threadIdx.x;
    int e = lane & 31, h = lane >> 5;
    const float* xr = x + (size_t)t * HH;
    float acc = 0.f;
    #pragma unroll 4
    for (int k = h; k < HH; k += 2)
        acc += xr[k] * gw[k * NE + e];
    acc += __shfl_down(acc, 32);

    __shared__ float sc[NE], sb[NE];
    if (lane < NE) {
        float s = 1.f / (1.f + expf(-acc));
        sc[e] = s;
        sb[e] = s + bias[e];
    }
    __syncthreads();
    if (lane == 0) {
        float gs[8];
        for (int g = 0; g < 8; g++) {
            float m1 = -1e30f, m2 = -1e30f;
            for (int j = 0; j < 4; j++) {
                float v = sb[g * 4 + j];
                if (v > m1) { m2 = m1; m1 = v; }
                else if (v > m2) { m2 = v; }
            }
            gs[g] = m1 + m2;
        }
        unsigned gmask = 0;
        for (int r = 0; r < 4; r++) {
            float best = -1e30f; int bi = 0;
            for (int g = 0; g < 8; g++)
                if (!((gmask >> g) & 1) && gs[g] > best) { best = gs[g]; bi = g; }
            gmask |= 1u << bi;
        }
        int ids[NTOPK]; float wsv[NTOPK]; float sum = 0.f;
        unsigned sel = 0;
        for (int r = 0; r < NTOPK; r++) {
            float best = -1e30f; int bi = 0;
            for (int ee = 0; ee < NE; ee++) {
                if (!((gmask >> (ee >> 2)) & 1)) continue;
                if ((sel >> ee) & 1) continue;
                if (sb[ee] > best) { best = sb[ee]; bi = ee; }
            }
            sel |= 1u << bi;
            ids[r] = bi; wsv[r] = sc[bi]; sum += sc[bi];
        }
        float inv = SCALEF / sum;
        for (int r = 0; r < NTOPK; r++) {
            int ee = ids[r];
            int slot = atomicAdd(&cnt[ee], 1);
            tlist[(ee << 10) + slot] = t;
            twgt[(ee << 10) + slot] = wsv[r] * inv;
        }
    }
}

// ---------------------------------------------------------------------------
// Kernel 3: gate_up GEMM + silu*mul + weight, bf16 MFMA 16x16x32.
// Software-pipelined: double-buffered LDS; prefetch (GLD16 A + W float4 regs)
// issued AFTER the barrier, consumed next iteration -> one full iter of
// latency hiding; single barrier per K-step.
__global__ __launch_bounds__(256, 3)
void gu_gemm(const us* __restrict__ xb,
             const float* __restrict__ wgu, const float* __restrict__ shgu,
             const int* __restrict__ tlist, const float* __restrict__ twgt,
             const int* __restrict__ cnt, us* __restrict__ act) {
    int e = blockIdx.z;
    int count = cnt[e];
    int m0 = blockIdx.y * 128;
    if (m0 >= count) return;
    int n0 = blockIdx.x * 64;
    const float* wb = (e < NE) ? (wgu + (size_t)e * HH * (2 * II)) : shgu;
    const int* tl = tlist + (e << 10);

    __shared__ __align__(16) us xs[2][128 * 32];   // A tile [m][k] bf16
    __shared__ __align__(16) us wg[2][64 * 40];    // gate W [n][kpad=40]
    __shared__ __align__(16) us wu[2][64 * 40];    // up   W [n][kpad=40]

    int tid = threadIdx.x;
    int lane = tid & 63, wv = tid >> 6;
    int q = lane >> 4, c = lane & 15;

    // --- A staging: wave wv covers rows wv*16..+15 (buf half 0) and +64 (half 1)
    int arow = wv * 16 + (lane >> 2);
    int akc = (lane & 3) * 8;
    int tok0 = (m0 + arow < count) ? tl[m0 + arow] : 0;
    int tok1 = (m0 + arow + 64 < count) ? tl[m0 + arow + 64] : 0;
    const us* ag0 = xb + (size_t)tok0 * HH + akc;
    const us* ag1 = xb + (size_t)tok1 * HH + akc;
    int aoff0 = (wv * 16) * 32;        // wave-uniform LDS element offsets
    int aoff1 = (64 + wv * 16) * 32;

    // --- B staging mapping
    int kp = tid & 15, ig = tid >> 4;
    int n4 = ig * 4;
    const float* wpbase = wb + (size_t)(kp * 2) * (2 * II) + n0 + n4;
    int di = n4 * 20 + kp;             // dword idx, row = 20 dwords

    f32x4 accg[2][4] = {};
    f32x4 accu[2][4] = {};

    // prologue: prefetch k0=0 into buf 0 / regs
    GLD16(ag0, xs[0] + aoff0);
    GLD16(ag1, xs[0] + aoff1);
    float4 g0 = *(const float4*)(wpbase);
    float4 g1 = *(const float4*)(wpbase + 2 * II);
    float4 u0 = *(const float4*)(wpbase + II);
    float4 u1 = *(const float4*)(wpbase + 2 * II + II);

    int cur = 0;
    for (int k0 = 0; k0 < HH; k0 += 32) {
        // stage W(k0) regs -> LDS[cur]
        unsigned* wgd = (unsigned*)wg[cur];
        unsigned* wud = (unsigned*)wu[cur];
        wgd[di]      = pack2(g0.x, g1.x);
        wgd[di + 20] = pack2(g0.y, g1.y);
        wgd[di + 40] = pack2(g0.z, g1.z);
        wgd[di + 60] = pack2(g0.w, g1.w);
        wud[di]      = pack2(u0.x, u1.x);
        wud[di + 20] = pack2(u0.y, u1.y);
        wud[di + 40] = pack2(u0.z, u1.z);
        wud[di + 60] = pack2(u0.w, u1.w);
        __syncthreads();   // drains prev-iter GLD16 (latency hidden) + LDS writes

        int k1 = k0 + 32;
        if (k1 < HH) {     // prefetch next tile (issued after barrier, used next iter)
            GLD16(ag0 + k1, xs[cur ^ 1] + aoff0);
            GLD16(ag1 + k1, xs[cur ^ 1] + aoff1);
            const float* wp = wpbase + (size_t)k1 * (2 * II);
            g0 = *(const float4*)(wp);
            g1 = *(const float4*)(wp + 2 * II);
            u0 = *(const float4*)(wp + II);
            u1 = *(const float4*)(wp + 2 * II + II);
        }

        const us* xsc = xs[cur];
        const us* wgc = wg[cur];
        const us* wuc = wu[cur];
        bf16x8 a0 = *(const bf16x8*)(xsc + (wv * 32 + c) * 32 + q * 8);
        bf16x8 a1 = *(const bf16x8*)(xsc + (wv * 32 + 16 + c) * 32 + q * 8);
        #pragma unroll
        for (int tn = 0; tn < 4; tn++) {
            bf16x8 bg = *(const bf16x8*)(wgc + (tn * 16 + c) * 40 + q * 8);
            bf16x8 bu = *(const bf16x8*)(wuc + (tn * 16 + c) * 40 + q * 8);
            accg[0][tn] = __builtin_amdgcn_mfma_f32_16x16x32_bf16(a0, bg, accg[0][tn], 0, 0, 0);
            accg[1][tn] = __builtin_amdgcn_mfma_f32_16x16x32_bf16(a1, bg, accg[1][tn], 0, 0, 0);
            accu[0][tn] = __builtin_amdgcn_mfma_f32_16x16x32_bf16(a0, bu, accu[0][tn], 0, 0, 0);
            accu[1][tn] = __builtin_amdgcn_mfma_f32_16x16x32_bf16(a1, bu, accu[1][tn], 0, 0, 0);
        }
        cur ^= 1;
    }

    // epilogue: act = silu(g)*u * weight, bf16 store
    const float* twp = twgt + (e << 10);
    #pragma unroll
    for (int tm = 0; tm < 2; tm++) {
        int mlb = wv * 32 + tm * 16 + q * 4;
        #pragma unroll
        for (int r = 0; r < 4; r++) {
            int m = m0 + mlb + r;
            if (m < count) {
                float w = twp[m];
                size_t rowbase = ((size_t)(e << 10) + m) * II + n0;
                #pragma unroll
                for (int tn = 0; tn < 4; tn++) {
                    float g = accg[tm][tn][r];
                    float u = accu[tm][tn][r];
                    float a = (g / (1.f + __expf(-g))) * u * w;
                    act[rowbase + tn * 16 + c] = (us)bf16rne(a);
                }
            }
        }
    }
}

// ---------------------------------------------------------------------------
// Kernel 4: down GEMM + scatter-add into out, same pipelined structure.
__global__ __launch_bounds__(256, 3)
void down_gemm(const us* __restrict__ act,
               const float* __restrict__ wd, const float* __restrict__ shd,
               const int* __restrict__ tlist, const int* __restrict__ cnt,
               float* __restrict__ out) {
    int e = blockIdx.z;
    int count = cnt[e];
    int m0 = blockIdx.y * 128;
    if (m0 >= count) return;
    int n0 = blockIdx.x * 128;
    const float* wb = (e < NE) ? (wd + (size_t)e * II * HH) : shd;
    const int* tl = tlist + (e << 10);

    __shared__ __align__(16) us as_[2][128 * 32];
    __shared__ __align__(16) us bs[2][128 * 40];

    int tid = threadIdx.x;
    int lane = tid & 63, wv = tid >> 6;
    int q = lane >> 4, c = lane & 15;

    const us* ag =
        act + ((size_t)(e << 10) + m0 + wv * 16 + (lane >> 2)) * II + (lane & 3) * 8;
    int aoff0 = (wv * 16) * 32;
    int aoff1 = (64 + wv * 16) * 32;

    int kp = tid & 15, ig = tid >> 4;
    int n4 = ig * 4;
    const float* wpbase = wb + (size_t)(kp * 2) * HH + n0 + n4;
    int di0 = n4 * 20 + kp;
    int di1 = (n4 + 64) * 20 + kp;

    f32x4 acc[2][8] = {};

    GLD16(ag, as_[0] + aoff0);
    GLD16(ag + (size_t)64 * II, as_[0] + aoff1);
    float4 x0 = *(const float4*)(wpbase);
    float4 x1 = *(const float4*)(wpbase + HH);
    float4 y0 = *(const float4*)(wpbase + 64);
    float4 y1 = *(const float4*)(wpbase + HH + 64);

    int cur = 0;
    for (int k0 = 0; k0 < II; k0 += 32) {
        unsigned* bd = (unsigned*)bs[cur];
        bd[di0]      = pack2(x0.x, x1.x);
        bd[di0 + 20] = pack2(x0.y, x1.y);
        bd[di0 + 40] = pack2(x0.z, x1.z);
        bd[di0 + 60] = pack2(x0.w, x1.w);
        bd[di1]      = pack2(y0.x, y1.x);
        bd[di1 + 20] = pack2(y0.y, y1.y);
        bd[di1 + 40] = pack2(y0.z, y1.z);
        bd[di1 + 60] = pack2(y0.w, y1.w);
        __syncthreads();

        int k1 = k0 + 32;
        if (k1 < II) {
            GLD16(ag + k1, as_[cur ^ 1] + aoff0);
            GLD16(ag + (size_t)64 * II + k1, as_[cur ^ 1] + aoff1);
            const float* wp = wpbase + (size_t)k1 * HH;
            x0 = *(const float4*)(wp);
            x1 = *(const float4*)(wp + HH);
            y0 = *(const float4*)(wp + 64);
            y1 = *(const float4*)(wp + HH + 64);
        }

        const us* asc = as_[cur];
        const us* bsc = bs[cur];
        bf16x8 a0 = *(const bf16x8*)(asc + (wv * 32 + c) * 32 + q * 8);
        bf16x8 a1 = *(const bf16x8*)(asc + (wv * 32 + 16 + c) * 32 + q * 8);
        #pragma unroll
        for (int tn = 0; tn < 8; tn++) {
            bf16x8 b = *(const bf16x8*)(bsc + (tn * 16 + c) * 40 + q * 8);
            acc[0][tn] = __builtin_amdgcn_mfma_f32_16x16x32_bf16(a0, b, acc[0][tn], 0, 0, 0);
            acc[1][tn] = __builtin_amdgcn_mfma_f32_16x16x32_bf16(a1, b, acc[1][tn], 0, 0, 0);
        }
        cur ^= 1;
    }

    #pragma unroll
    for (int tm = 0; tm < 2; tm++) {
        int mlb = wv * 32 + tm * 16 + q * 4;
        #pragma unroll
        for (int r = 0; r < 4; r++) {
            int m = m0 + mlb + r;
            if (m < count) {
                int tok = tl[m];
                float* op = out + (size_t)tok * HH + n0 + c;
                #pragma unroll
                for (int tn = 0; tn < 8; tn++)
                    unsafeAtomicAdd(op + tn * 16, acc[tm][tn][r]);
            }
        }
    }
}

// ---------------------------------------------------------------------------
extern "C" void kernel_launch(void* const* d_in, const int* in_sizes, int n_in,
                              void* d_out, int out_size, void* d_ws, size_t ws_size,
                              hipStream_t stream) {
    const float* x    = (const float*)d_in[0];
    const float* gw   = (const float*)d_in[1];
    const float* bias = (const float*)d_in[2];
    const float* wgu  = (const float*)d_in[3];
    const float* wd   = (const float*)d_in[4];
    const float* shgu = (const float*)d_in[5];
    const float* shd  = (const float*)d_in[6];
    float* out = (float*)d_out;

    // workspace layout (~74 MB total)
    char* ws = (char*)d_ws;
    int*   cnt   = (int*)ws;                                   // 256 B (33 used)
    int*   tlist = (int*)(ws + 256);                           // 33*1024*4
    float* twgt  = (float*)(ws + 256 + 33 * 1024 * 4);         // 33*1024*4
    us* xb  = (us*)(ws + 256 + 2 * 33 * 1024 * 4);
    us* act = (us*)((char*)xb + (size_t)TT * HH * 2);

    hipMemsetAsync(cnt, 0, 256, stream);
    hipMemsetAsync(out, 0, (size_t)out_size * sizeof(float), stream);
    init_convert<<<dim3((TT * HH / 4) / 256), 256, 0, stream>>>(x, xb, cnt, tlist, twgt);
    router_kernel<<<dim3(TT), 64, 0, stream>>>(x, gw, bias, cnt, tlist, twgt);
    gu_gemm<<<dim3(II / 64, 8, NE + 1), 256, 0, stream>>>(xb, wgu, shgu, tlist, twgt, cnt, act);
    down_gemm<<<dim3(HH / 128, 8, NE + 1), 256, 0, stream>>>(act, wd, shd, tlist, cnt, out);
}